// Round 10
// baseline (191.081 us; speedup 1.0000x reference)
//
#include <hip/hip_runtime.h>
#include <cstdint>
#include <cstddef>

// x[B=512, L=32, H=32, D=128]; per (l,h): Linear(128->128) -> GELU -> Linear(128->128)
// Persistent-per-lh (R9) + R10: 512-thread blocks (16 waves/CU) + deferred
// stores (prev tile's output stored right after the loop-top barrier so the
// vmcnt(0) drain overlaps GEMM1 instead of stalling every wave).
#define LH      1024
#define Dd      128
#define BT      64            // batch rows per tile -> 32 KB f32 in LDS
#define NTILE   8             // 512 / 64
#define XSTRIDE (LH * Dd)

typedef __attribute__((ext_vector_type(8))) short bf16x8;
typedef __attribute__((ext_vector_type(4))) float f32x4;
typedef const __attribute__((address_space(1))) uint32_t gu32;
typedef __attribute__((address_space(3))) uint32_t lu32;

static __device__ __forceinline__ short f2bf(float f) {
  return __builtin_bit_cast(short, (__bf16)f);
}

// tanh-form GELU as one sigmoid; |diff| vs erf-gelu ~3e-3 << 0.185 threshold
static __device__ __forceinline__ float gelu_fast(float v) {
  float v2 = v * v;
  float u2 = v * (1.5957691216f + 0.0713548163f * v2);
  return v / (1.0f + __expf(-u2));
}

__global__ __launch_bounds__(512, 4) void fused_mlp_persist(
    const float* __restrict__ x, const float* __restrict__ W1,
    const float* __restrict__ b1, const float* __restrict__ W2,
    const float* __restrict__ b2, float* __restrict__ out) {
  // 2 ping-pong buffers. Each: x f32 [64 rows][32 chunks of 16B], chunk-index
  // XOR-swizzled on the GLOBAL source addr (global_load_lds writes LDS
  // linearly, m104/m173). H bf16 [64][128] overlays bytes 0..16K of the
  // CURRENT buffer after GEMM1's reads are barrier-complete.
  __shared__ alignas(16) char smem[2][BT * Dd * 4];   // 64 KB -> 2 blocks/CU

  const int tid  = threadIdx.x;
  const int lane = tid & 63;
  const int wid  = tid >> 6;     // 8 waves, each owns 16 N-columns
  const int lr   = lane & 15;
  const int lg   = lane >> 4;

  const int lh = blockIdx.x;     // W reuse is intra-block
  const int n0 = wid * 16;

  const float* w1  = W1 + (size_t)lh * (Dd * Dd);
  const float* w2  = W2 + (size_t)lh * (Dd * Dd);
  const float* xlh = x   + (size_t)lh * Dd;
  float*       olh = out + (size_t)lh * Dd;

  // stage tile t into buffer buf: 4 DMA issues/wave (32 KB/block in flight)
  auto stage = [&](int t, int buf) {
#pragma unroll
    for (int i = 0; i < 4; ++i) {
      const int slot = wid * 4 + i;          // wave-uniform 1KB LDS slot
      const int row  = slot * 2 + (lane >> 5);
      const int cp   = lane & 31;            // chunk position in LDS
      const int c    = cp ^ (row & 15);      // global chunk (bijective swz)
      const float* g = xlh + (size_t)(t * BT + row) * XSTRIDE + c * 4;
      __builtin_amdgcn_global_load_lds((gu32*)g,
                                       (lu32*)(smem[buf] + slot * 1024),
                                       16, 0, 0);
    }
  };

  // ---- prologue: DMA tile 0; gather this wave's W fragments to regs
  // (once per block, hidden under the DMA flight); biases.
  stage(0, 0);

  bf16x8 bw1[4], bw2[4];
#pragma unroll
  for (int ks = 0; ks < 4; ++ks) {
    const float* p1 = w1 + (size_t)(ks * 32 + lg * 8) * Dd + n0 + lr;
    const float* p2 = w2 + (size_t)(ks * 32 + lg * 8) * Dd + n0 + lr;
    bf16x8 a, b;
#pragma unroll
    for (int j = 0; j < 8; ++j) { a[j] = f2bf(p1[j * Dd]); b[j] = f2bf(p2[j * Dd]); }
    bw1[ks] = a;
    bw2[ks] = b;
  }

  const float bb1 = b1[lh * Dd + n0 + lr];
  const float bb2 = b2[lh * Dd + n0 + lr];

  f32x4 accp[4];   // previous tile's GEMM2 result, stored one tile late

  for (int t = 0; t < NTILE; ++t) {
    const int cur = t & 1;

    // Loop-top barrier: drains DMA(t) -> x[t] visible; proves all waves done
    // with smem[cur^1] (GEMM2(t-1) reads) so stage(t+1) may overwrite it.
    __syncthreads();
    if (t + 1 < NTILE) stage(t + 1, cur ^ 1);

    // Deferred store of tile t-1: issued here so the stores drain during
    // GEMM1(t) instead of stalling at the very next barrier (R9 stall #1).
    if (t > 0) {
      float* ob = olh + (size_t)((t - 1) * BT) * XSTRIDE;
#pragma unroll
      for (int mt = 0; mt < 4; ++mt)
#pragma unroll
        for (int r = 0; r < 4; ++r) {
          const int b = mt * 16 + lg * 4 + r;
          ob[(size_t)b * XSTRIDE + n0 + lr] = accp[mt][r];
        }
    }

    // ---------------- GEMM1: H = gelu(X @ W1 + b1) ----------------
    f32x4 acc[4];
#pragma unroll
    for (int mt = 0; mt < 4; ++mt) acc[mt] = (f32x4){bb1, bb1, bb1, bb1};
#pragma unroll
    for (int ks = 0; ks < 4; ++ks) {
      bf16x8 af[4];
#pragma unroll
      for (int mt = 0; mt < 4; ++mt) {
        const int row = mt * 16 + lr;
        const int c0  = ks * 8 + lg * 2;
        const int m   = row & 15;
        const float4 lo = *(const float4*)(smem[cur] + row * 512 + ((c0)     ^ m) * 16);
        const float4 hi = *(const float4*)(smem[cur] + row * 512 + ((c0 + 1) ^ m) * 16);
        bf16x8 a;
        a[0] = f2bf(lo.x); a[1] = f2bf(lo.y); a[2] = f2bf(lo.z); a[3] = f2bf(lo.w);
        a[4] = f2bf(hi.x); a[5] = f2bf(hi.y); a[6] = f2bf(hi.z); a[7] = f2bf(hi.w);
        af[mt] = a;
      }
#pragma unroll
      for (int mt = 0; mt < 4; ++mt)
        acc[mt] = __builtin_amdgcn_mfma_f32_16x16x32_bf16(af[mt], bw1[ks], acc[mt], 0, 0, 0);
    }

    // GELU in regs, then overlay-write H into smem[cur]
    short hv[4][4];
#pragma unroll
    for (int mt = 0; mt < 4; ++mt)
#pragma unroll
      for (int r = 0; r < 4; ++r)
        hv[mt][r] = f2bf(gelu_fast(acc[mt][r]));

    __syncthreads();   // all waves done reading x[cur] -> safe to overlay H

#pragma unroll
    for (int mt = 0; mt < 4; ++mt) {
      const int e = n0 + lr;
#pragma unroll
      for (int r = 0; r < 4; ++r) {
        const int b = mt * 16 + lg * 4 + r;    // C/D row = (lane>>4)*4 + reg
        const int off = (b * 256 + e * 2) ^ ((b & 7) << 4);
        *(short*)(smem[cur] + off) = hv[mt][r];
      }
    }
    __syncthreads();   // H visible

    // ---------------- GEMM2: out = H @ W2 + b2 (W2 in regs) ----------
    f32x4 acc2[4];
#pragma unroll
    for (int mt = 0; mt < 4; ++mt) acc2[mt] = (f32x4){bb2, bb2, bb2, bb2};
#pragma unroll
    for (int ks = 0; ks < 4; ++ks) {
      const int k2 = (ks * 32 + lg * 8) * 2;   // byte offset of 16B H granule
#pragma unroll
      for (int mt = 0; mt < 4; ++mt) {
        const int b = mt * 16 + lr;
        const int off = (b * 256 + k2) ^ ((b & 7) << 4);
        bf16x8 a = *(const bf16x8*)(smem[cur] + off);
        acc2[mt] = __builtin_amdgcn_mfma_f32_16x16x32_bf16(a, bw2[ks], acc2[mt], 0, 0, 0);
      }
    }
#pragma unroll
    for (int mt = 0; mt < 4; ++mt) accp[mt] = acc2[mt];
  }

  // final tile's deferred store
  {
    float* ob = olh + (size_t)((NTILE - 1) * BT) * XSTRIDE;
#pragma unroll
    for (int mt = 0; mt < 4; ++mt)
#pragma unroll
      for (int r = 0; r < 4; ++r) {
        const int b = mt * 16 + lg * 4 + r;
        ob[(size_t)b * XSTRIDE + n0 + lr] = accp[mt][r];
      }
  }
}

extern "C" void kernel_launch(void* const* d_in, const int* in_sizes, int n_in,
                              void* d_out, int out_size, void* d_ws, size_t ws_size,
                              hipStream_t stream) {
  (void)in_sizes; (void)n_in; (void)d_ws; (void)ws_size; (void)out_size;
  const float* x  = (const float*)d_in[0];
  const float* W1 = (const float*)d_in[1];
  const float* b1 = (const float*)d_in[2];
  const float* W2 = (const float*)d_in[3];
  const float* b2 = (const float*)d_in[4];
  float* out = (float*)d_out;
  fused_mlp_persist<<<dim3(LH), dim3(512), 0, stream>>>(x, W1, b1, W2, b2, out);
}

// Round 11
// 153.008 us; speedup vs baseline: 1.2488x; 1.2488x over previous
//
#include <hip/hip_runtime.h>
#include <cstdint>
#include <cstddef>

// x[B=512, L=32, H=32, D=128]; per (l,h): Linear(128->128) -> GELU -> Linear(128->128)
// R9 persistent-per-lh structure + R11: counted-vmcnt barriers (T3/T4, m201/m218).
// __syncthreads() = s_waitcnt vmcnt(0) lgkmcnt(0) + s_barrier -> drained our own
// output stores 3x/tile. Raw s_barrier + counted waits keep stores in flight.
#define LH      1024
#define Dd      128
#define BT      64            // batch rows per tile -> 32 KB f32 in LDS
#define NTILE   8             // 512 / 64
#define XSTRIDE (LH * Dd)

typedef __attribute__((ext_vector_type(8))) short bf16x8;
typedef __attribute__((ext_vector_type(4))) float f32x4;
typedef const __attribute__((address_space(1))) uint32_t gu32;
typedef __attribute__((address_space(3))) uint32_t lu32;

static __device__ __forceinline__ short f2bf(float f) {
  return __builtin_bit_cast(short, (__bf16)f);
}

// tanh-form GELU as one sigmoid; |diff| vs erf-gelu ~3e-3 << 0.185 threshold
static __device__ __forceinline__ float gelu_fast(float v) {
  float v2 = v * v;
  float u2 = v * (1.5957691216f + 0.0713548163f * v2);
  return v / (1.0f + __expf(-u2));
}

// LDS-only barrier: ds ops drained, global loads/stores stay in flight.
#define BAR_LGKM() do {                                          \
  __builtin_amdgcn_sched_barrier(0);                             \
  asm volatile("s_waitcnt lgkmcnt(0)" ::: "memory");             \
  __builtin_amdgcn_s_barrier();                                  \
  __builtin_amdgcn_sched_barrier(0);                             \
} while (0)

// End-of-iter barrier: vmcnt(32) retires (in-order, m135) everything except
// the newest 32 vmem ops = this tile's 32 output stores -> next tile's DMA
// (8 oldest) proven complete, stores keep draining under next GEMM1.
#define BAR_END() do {                                           \
  __builtin_amdgcn_sched_barrier(0);                             \
  asm volatile("s_waitcnt vmcnt(32) lgkmcnt(0)" ::: "memory");   \
  __builtin_amdgcn_s_barrier();                                  \
  __builtin_amdgcn_sched_barrier(0);                             \
} while (0)

__global__ __launch_bounds__(256, 2) void fused_mlp_persist(
    const float* __restrict__ x, const float* __restrict__ W1,
    const float* __restrict__ b1, const float* __restrict__ W2,
    const float* __restrict__ b2, float* __restrict__ out) {
  // 2 ping-pong buffers. Each: x f32 [64 rows][32 chunks of 16B], chunk-index
  // XOR-swizzled on the GLOBAL source addr (global_load_lds writes LDS
  // linearly, m104/m173). H bf16 [64][128] overlays bytes 0..16K of the
  // CURRENT buffer after GEMM1's reads are barrier-complete.
  __shared__ alignas(16) char smem[2][BT * Dd * 4];   // 64 KB -> 2 blocks/CU

  const int tid  = threadIdx.x;
  const int lane = tid & 63;
  const int wid  = tid >> 6;     // 4 waves, each owns 32 N-columns (R9 proven)
  const int lr   = lane & 15;
  const int lg   = lane >> 4;

  const int lh = blockIdx.x;     // W reuse is intra-block
  const int n0 = wid * 32;

  const float* w1  = W1 + (size_t)lh * (Dd * Dd);
  const float* w2  = W2 + (size_t)lh * (Dd * Dd);
  const float* xlh = x   + (size_t)lh * Dd;
  float*       olh = out + (size_t)lh * Dd;

  // stage tile t into buffer buf: 8 DMA issues/wave, 32 KB in flight
  auto stage = [&](int t, int buf) {
#pragma unroll
    for (int i = 0; i < 8; ++i) {
      const int slot = wid * 8 + i;          // wave-uniform 1KB LDS slot
      const int row  = slot * 2 + (lane >> 5);
      const int cp   = lane & 31;            // chunk position in LDS
      const int c    = cp ^ (row & 15);      // global chunk (bijective swz)
      const float* g = xlh + (size_t)(t * BT + row) * XSTRIDE + c * 4;
      __builtin_amdgcn_global_load_lds((gu32*)g,
                                       (lu32*)(smem[buf] + slot * 1024),
                                       16, 0, 0);
    }
  };

  // ---- prologue: DMA tile 0; gather ALL W fragments to regs (once per
  // block, hidden under the DMA flight); biases.
  stage(0, 0);

  bf16x8 bw1[4][2], bw2[4][2];
#pragma unroll
  for (int ks = 0; ks < 4; ++ks)
#pragma unroll
    for (int nt = 0; nt < 2; ++nt) {
      const float* p1 = w1 + (size_t)(ks * 32 + lg * 8) * Dd + n0 + nt * 16 + lr;
      const float* p2 = w2 + (size_t)(ks * 32 + lg * 8) * Dd + n0 + nt * 16 + lr;
      bf16x8 a, b;
#pragma unroll
      for (int j = 0; j < 8; ++j) { a[j] = f2bf(p1[j * Dd]); b[j] = f2bf(p2[j * Dd]); }
      bw1[ks][nt] = a;
      bw2[ks][nt] = b;
    }

  const float bb1_0 = b1[lh * Dd + n0 + lr];
  const float bb1_1 = b1[lh * Dd + n0 + 16 + lr];
  const float bb2_0 = b2[lh * Dd + n0 + lr];
  const float bb2_1 = b2[lh * Dd + n0 + 16 + lr];

  // prologue barrier: full drain (DMA(0) + W loads), once per block
  __builtin_amdgcn_sched_barrier(0);
  asm volatile("s_waitcnt vmcnt(0) lgkmcnt(0)" ::: "memory");
  __builtin_amdgcn_s_barrier();
  __builtin_amdgcn_sched_barrier(0);

  for (int t = 0; t < NTILE; ++t) {
    const int cur = t & 1;

    // DMA(t+1) -> other buffer; proven free by BAR_END(t-1) (lgkmcnt part).
    if (t + 1 < NTILE) stage(t + 1, cur ^ 1);

    // ---------------- GEMM1: H = gelu(X @ W1 + b1) ----------------
    f32x4 acc[4][2];
#pragma unroll
    for (int mt = 0; mt < 4; ++mt) {
      acc[mt][0] = (f32x4){bb1_0, bb1_0, bb1_0, bb1_0};
      acc[mt][1] = (f32x4){bb1_1, bb1_1, bb1_1, bb1_1};
    }
#pragma unroll
    for (int ks = 0; ks < 4; ++ks) {
      bf16x8 af[4];
#pragma unroll
      for (int mt = 0; mt < 4; ++mt) {
        const int row = mt * 16 + lr;
        const int c0  = ks * 8 + lg * 2;
        const int m   = row & 15;
        const float4 lo = *(const float4*)(smem[cur] + row * 512 + ((c0)     ^ m) * 16);
        const float4 hi = *(const float4*)(smem[cur] + row * 512 + ((c0 + 1) ^ m) * 16);
        bf16x8 a;
        a[0] = f2bf(lo.x); a[1] = f2bf(lo.y); a[2] = f2bf(lo.z); a[3] = f2bf(lo.w);
        a[4] = f2bf(hi.x); a[5] = f2bf(hi.y); a[6] = f2bf(hi.z); a[7] = f2bf(hi.w);
        af[mt] = a;
      }
#pragma unroll
      for (int mt = 0; mt < 4; ++mt)
#pragma unroll
        for (int nt = 0; nt < 2; ++nt)
          acc[mt][nt] = __builtin_amdgcn_mfma_f32_16x16x32_bf16(af[mt], bw1[ks][nt], acc[mt][nt], 0, 0, 0);
    }

    // GELU in regs before the barrier
    short hv[4][2][4];
#pragma unroll
    for (int mt = 0; mt < 4; ++mt)
#pragma unroll
      for (int nt = 0; nt < 2; ++nt)
#pragma unroll
        for (int r = 0; r < 4; ++r)
          hv[mt][nt][r] = f2bf(gelu_fast(acc[mt][nt][r]));

    BAR_LGKM();   // all waves done reading x[cur]; stores/DMA stay in flight

#pragma unroll
    for (int mt = 0; mt < 4; ++mt)
#pragma unroll
      for (int nt = 0; nt < 2; ++nt) {
        const int e = n0 + nt * 16 + lr;
#pragma unroll
        for (int r = 0; r < 4; ++r) {
          const int b = mt * 16 + lg * 4 + r;   // C/D row = (lane>>4)*4 + reg
          const int off = (b * 256 + e * 2) ^ ((b & 7) << 4);
          *(short*)(smem[cur] + off) = hv[mt][nt][r];
        }
      }

    BAR_LGKM();   // H visible; stores/DMA still in flight

    // ---------------- GEMM2: out = H @ W2 + b2 (W2 in regs) ----------
    f32x4 acc2[4][2];
#pragma unroll
    for (int mt = 0; mt < 4; ++mt) {
      acc2[mt][0] = (f32x4){bb2_0, bb2_0, bb2_0, bb2_0};
      acc2[mt][1] = (f32x4){bb2_1, bb2_1, bb2_1, bb2_1};
    }
#pragma unroll
    for (int ks = 0; ks < 4; ++ks) {
      const int k2 = (ks * 32 + lg * 8) * 2;   // byte offset of 16B H granule
#pragma unroll
      for (int mt = 0; mt < 4; ++mt) {
        const int b = mt * 16 + lr;
        const int off = (b * 256 + k2) ^ ((b & 7) << 4);
        bf16x8 a = *(const bf16x8*)(smem[cur] + off);
#pragma unroll
        for (int nt = 0; nt < 2; ++nt)
          acc2[mt][nt] = __builtin_amdgcn_mfma_f32_16x16x32_bf16(a, bw2[ks][nt], acc2[mt][nt], 0, 0, 0);
      }
    }

    // epilogue: 32 f32 stores (64B contiguous per 16-lane group)
    {
      float* ob = olh + (size_t)(t * BT) * XSTRIDE;
#pragma unroll
      for (int mt = 0; mt < 4; ++mt)
#pragma unroll
        for (int nt = 0; nt < 2; ++nt) {
          const int e = n0 + nt * 16 + lr;
#pragma unroll
          for (int r = 0; r < 4; ++r) {
            const int b = mt * 16 + lg * 4 + r;
            ob[(size_t)b * XSTRIDE + e] = acc2[mt][nt][r];
          }
        }
    }

    // end-of-iter: drain DMA(t+1) (8 oldest) + stores(t-1); keep this tile's
    // 32 stores in flight across the barrier.
    if (t + 1 < NTILE) BAR_END();
  }
}

extern "C" void kernel_launch(void* const* d_in, const int* in_sizes, int n_in,
                              void* d_out, int out_size, void* d_ws, size_t ws_size,
                              hipStream_t stream) {
  (void)in_sizes; (void)n_in; (void)d_ws; (void)ws_size; (void)out_size;
  const float* x  = (const float*)d_in[0];
  const float* W1 = (const float*)d_in[1];
  const float* b1 = (const float*)d_in[2];
  const float* W2 = (const float*)d_in[3];
  const float* b2 = (const float*)d_in[4];
  float* out = (float*)d_out;
  fused_mlp_persist<<<dim3(LH), dim3(256), 0, stream>>>(x, W1, b1, W2, b2, out);
}